// Round 1
// baseline (3849.018 us; speedup 1.0000x reference)
//
#include <hip/hip_runtime.h>

static constexpr int Bc  = 8;
static constexpr int Sc  = 2048;
static constexpr int Hc  = 4;
static constexpr int DKc = 64;
static constexpr int DMc = 256;

__device__ __forceinline__ float waveReduceMax(float v) {
#pragma unroll
  for (int o = 32; o > 0; o >>= 1) v = fmaxf(v, __shfl_down(v, o, 64));
  return v;
}
__device__ __forceinline__ float waveReduceSum(float v) {
#pragma unroll
  for (int o = 32; o > 0; o >>= 1) v += __shfl_down(v, o, 64);
  return v;
}

// One block per (b,s). Computes qs[b,h,s,e], ksT[b,h,e,s] (transposed K for
// coalesced score reads), vs[b,s,e].
__global__ __launch_bounds__(256) void proj_kernel(
    const float* __restrict__ q, const float* __restrict__ k, const float* __restrict__ v,
    const float* __restrict__ Wq, const float* __restrict__ bq,
    const float* __restrict__ Wk, const float* __restrict__ bk,
    const float* __restrict__ Wv, const float* __restrict__ bv,
    float* __restrict__ qs, float* __restrict__ ksT, float* __restrict__ vs) {
  const int bs  = blockIdx.x;          // b*S + s
  const int b   = bs >> 11;
  const int s   = bs & (Sc - 1);
  const int tid = threadIdx.x;
  __shared__ float qrow[DMc], krow[DMc], vrow[DMc];
  qrow[tid] = q[(size_t)bs * DMc + tid];
  krow[tid] = k[(size_t)bs * DMc + tid];
  vrow[tid] = v[(size_t)bs * DMc + tid];
  __syncthreads();
  const int h = tid >> 6, e = tid & 63;
  const float4* wq4 = (const float4*)(Wq + (size_t)(h * DKc + e) * DMc);
  const float4* wk4 = (const float4*)(Wk + (size_t)(h * DKc + e) * DMc);
  const float4* q4  = (const float4*)qrow;
  const float4* k4  = (const float4*)krow;
  float accq = 0.f, acck = 0.f;
#pragma unroll 8
  for (int i = 0; i < DMc / 4; ++i) {
    float4 a = q4[i], wa = wq4[i];
    accq += a.x * wa.x + a.y * wa.y + a.z * wa.z + a.w * wa.w;
    float4 c = k4[i], wc = wk4[i];
    acck += c.x * wc.x + c.y * wc.y + c.z * wc.z + c.w * wc.w;
  }
  qs[((size_t)(b * Hc + h) * Sc + s) * DKc + e]  = accq + bq[h * DKc + e];
  ksT[((size_t)(b * Hc + h) * DKc + e) * Sc + s] = acck + bk[h * DKc + e];
  if (h == 0) {
    const float4* wv4 = (const float4*)(Wv + (size_t)e * DMc);
    const float4* v4  = (const float4*)vrow;
    float accv = 0.f;
#pragma unroll 8
    for (int i = 0; i < DMc / 4; ++i) {
      float4 a = v4[i], wa = wv4[i];
      accv += a.x * wa.x + a.y * wa.y + a.z * wa.z + a.w * wa.w;
    }
    vs[(size_t)bs * DKc + e] = accv + bv[e];
  }
}

// One block per (b,h,q): scores -> softmax -> write attn row -> PV into heads.
__global__ __launch_bounds__(256) void attn_kernel(
    const float* __restrict__ qs, const float* __restrict__ ksT,
    const float* __restrict__ vs, float* __restrict__ attn,
    float* __restrict__ heads) {
  const int qidx = blockIdx.x;
  const int h    = blockIdx.y;
  const int b    = blockIdx.z;
  const int tid  = threadIdx.x;
  __shared__ float qrow[DKc];
  __shared__ float sc[Sc];          // 8 KB
  __shared__ float wred[4];
  __shared__ float sred[4];
  __shared__ float hred[256];
  if (tid < DKc) qrow[tid] = qs[((size_t)(b * Hc + h) * Sc + qidx) * DKc + tid];
  __syncthreads();

  const float4* ksT4 = (const float4*)(ksT + (size_t)(b * Hc + h) * DKc * Sc);
  float4* sc4 = (float4*)sc;
  float lmax = -1e30f;
#pragma unroll
  for (int j = 0; j < 2; ++j) {
    const int k4 = tid + j * 256;   // float4 column index (512 per row)
    float4 acc = make_float4(0.f, 0.f, 0.f, 0.f);
#pragma unroll 8
    for (int e = 0; e < DKc; ++e) {
      const float qe = qrow[e];
      const float4 kv = ksT4[(size_t)e * (Sc / 4) + k4];
      acc.x += qe * kv.x; acc.y += qe * kv.y; acc.z += qe * kv.z; acc.w += qe * kv.w;
    }
    acc.x *= 0.125f; acc.y *= 0.125f; acc.z *= 0.125f; acc.w *= 0.125f;
    sc4[k4] = acc;
    lmax = fmaxf(lmax, fmaxf(fmaxf(acc.x, acc.y), fmaxf(acc.z, acc.w)));
  }
  float wm = waveReduceMax(lmax);
  if ((tid & 63) == 0) wred[tid >> 6] = wm;
  __syncthreads();
  const float gmax = fmaxf(fmaxf(wred[0], wred[1]), fmaxf(wred[2], wred[3]));

  float lsum = 0.f;
#pragma unroll
  for (int j = 0; j < 2; ++j) {
    const int k4 = tid + j * 256;
    float4 a = sc4[k4];
    a.x = __expf(a.x - gmax); a.y = __expf(a.y - gmax);
    a.z = __expf(a.z - gmax); a.w = __expf(a.w - gmax);
    sc4[k4] = a;
    lsum += a.x + a.y + a.z + a.w;
  }
  float wsum = waveReduceSum(lsum);
  if ((tid & 63) == 0) sred[tid >> 6] = wsum;
  __syncthreads();
  const float inv = 1.f / (sred[0] + sred[1] + sred[2] + sred[3]);

  float4* attnrow = (float4*)(attn + ((size_t)(b * Sc + qidx) * Hc + h) * Sc);
#pragma unroll
  for (int j = 0; j < 2; ++j) {
    const int k4 = tid + j * 256;
    float4 a = sc4[k4];
    a.x *= inv; a.y *= inv; a.z *= inv; a.w *= inv;
    sc4[k4] = a;
    attnrow[k4] = a;               // coalesced 536 MB total write
  }
  __syncthreads();

  // PV: heads[b,h,q,e] = sum_k sc[k] * vs[b,k,e]
  const int e = tid & 63;
  const int chunk = tid >> 6;      // 4 chunks of 512 k each
  const float* vsb = vs + (size_t)b * Sc * DKc;
  float acc = 0.f;
  const int k0 = chunk * 512;
#pragma unroll 4
  for (int kk = k0; kk < k0 + 512; ++kk) {
    acc += sc[kk] * vsb[(size_t)kk * DKc + e];
  }
  hred[tid] = acc;
  __syncthreads();
  if (chunk == 0) {
    float r = hred[e] + hred[64 + e] + hred[128 + e] + hred[192 + e];
    heads[((size_t)(b * Hc + h) * Sc + qidx) * DKc + e] = r;
  }
}

// One block per (b,s): mean over heads, project with Wh.
__global__ __launch_bounds__(256) void out_kernel(
    const float* __restrict__ heads, const float* __restrict__ Wh,
    float* __restrict__ out) {
  const int bs  = blockIdx.x;
  const int b   = bs >> 11;
  const int s   = bs & (Sc - 1);
  const int tid = threadIdx.x;
  __shared__ float havg[DKc];
  if (tid < DKc) {
    float a = 0.f;
#pragma unroll
    for (int h = 0; h < Hc; ++h)
      a += heads[((size_t)(b * Hc + h) * Sc + s) * DKc + tid];
    havg[tid] = a * 0.25f;
  }
  __syncthreads();
  const float4* wh4 = (const float4*)(Wh + (size_t)tid * DKc);
  const float4* h4  = (const float4*)havg;
  float acc = 0.f;
#pragma unroll
  for (int i = 0; i < DKc / 4; ++i) {
    float4 a = h4[i], w = wh4[i];
    acc += a.x * w.x + a.y * w.y + a.z * w.z + a.w * w.w;
  }
  out[(size_t)bs * DMc + tid] = acc;
}

extern "C" void kernel_launch(void* const* d_in, const int* in_sizes, int n_in,
                              void* d_out, int out_size, void* d_ws, size_t ws_size,
                              hipStream_t stream) {
  const float* q  = (const float*)d_in[0];
  const float* k  = (const float*)d_in[1];
  const float* v  = (const float*)d_in[2];
  const float* Wq = (const float*)d_in[3];
  const float* bq = (const float*)d_in[4];
  const float* Wk = (const float*)d_in[5];
  const float* bk = (const float*)d_in[6];
  const float* Wv = (const float*)d_in[7];
  const float* bv = (const float*)d_in[8];
  const float* Wh = (const float*)d_in[9];

  float* out  = (float*)d_out;                              // [B,S,256]
  float* attn = out + (size_t)Bc * Sc * DMc;                // [B,Sq,H,Sk]

  float* vs    = (float*)d_ws;                              // [B,S,64]      4 MB
  float* qs    = vs + (size_t)Bc * Sc * DKc;                // [B,H,S,64]   16 MB
  float* ksT   = qs + (size_t)Bc * Hc * Sc * DKc;           // [B,H,64,S]   16 MB
  float* heads = ksT + (size_t)Bc * Hc * Sc * DKc;          // [B,H,S,64]   16 MB

  proj_kernel<<<Bc * Sc, 256, 0, stream>>>(q, k, v, Wq, bq, Wk, bk, Wv, bv,
                                           qs, ksT, vs);
  attn_kernel<<<dim3(Sc, Hc, Bc), 256, 0, stream>>>(qs, ksT, vs, attn, heads);
  out_kernel<<<Bc * Sc, 256, 0, stream>>>(heads, Wh, out);
}